// Round 10
// baseline (527.123 us; speedup 1.0000x reference)
//
#include <hip/hip_runtime.h>
#include <cstdint>

// RGPR-GNN (GPR-GNN + RGCN basis-decomp convs) for MI355X.
// R21: R18 base (best verified 478.6us; transform-first R20 tied at 481 ->
// abandoned) + fixed-cost pool harvest:
//  - final_kernel DELETED: lin2 folded into the l=2 gemm_layer epilogue ONLY
//    (no out-RMW): h = b0 + t1*b1 + t2*curA + t3*c, out = h@w2 + b2. The b3
//    store is skipped (nothing reads it). -51.2MB read, -12.8MB write, -1 launch.
//  - scanB DELETED: scanC computes its own block base from raw blockSums
//    (<=6 loads/thread + tree reduce). -1 launch, no serial kernel.
//  - memset DELETED: prep_weights zeroes cntRel (grid covers NR).
// Per layer:
//   agg_reg:   one wave per dst, (dst,rel)-sorted edges, register accum.
//              5x-probed floor ~61us (MLP++, wave/seg, 2 fusions, transform).
//   gemm_layer: M=128 direct-A (R18), c=[curA|agg]@Wcat2+bias, relu l<2.
// Edge sort by (dst,rel) runs ONCE: hist(+rank) -> scanA/scanC -> placement.

constexpr int N_NODES  = 50000;
constexpr int E_EDGES  = 600000;
constexpr int R_REL    = 7;
constexpr int HID      = 128;
constexpr int IN_C     = 256;
constexpr int L_LAYERS = 3;
constexpr int AGG_COLS = 896;           // 7*128 aggregated message columns
constexpr int K_CAT    = 1024;          // 128 self + 896 agg
constexpr int NR       = N_NODES * R_REL;            // 350000 segments
constexpr int SCANR_BLOCKS = (NR + 255) / 256;       // 1368
constexpr int WCAT_ELEMS = L_LAYERS * 128 * K_CAT;   // 393216

#define DEVI __device__ __forceinline__

using short8  = __attribute__((ext_vector_type(8))) short;
using floatx4 = __attribute__((ext_vector_type(4))) float;

DEVI unsigned short f2bf(float f) {
  unsigned u = __float_as_uint(f);
  unsigned r = (u + 0x7FFFu + ((u >> 16) & 1u)) >> 16;  // RNE
  return (unsigned short)r;
}
DEVI float bf2f(unsigned short h) { return __uint_as_float(((unsigned)h) << 16); }

// ---------------------------------------------------------------- weight prep
// t < WCAT_ELEMS: wcat2T[L][f=128][k=1024]; else w1T [128][256].
// Also zeroes cntRel[t] for t < NR (replaces the memset dispatch).
__global__ __launch_bounds__(256) void prep_weights(
    const float* __restrict__ w1,
    const float* __restrict__ comps,   // [L,R,8]
    const float* __restrict__ bases,   // [L,8,128,128]
    const float* __restrict__ roots,   // [L,128,128]
    unsigned short* __restrict__ w1T,
    unsigned short* __restrict__ wcat2T,
    int* __restrict__ cntRel)
{
  int t = blockIdx.x * 256 + threadIdx.x;
  if (t < NR) cntRel[t] = 0;
  if (t < WCAT_ELEMS) {
    int l   = t >> 17;
    int rem = t & 131071;
    int f   = rem >> 10;
    int k   = rem & 1023;
    float v;
    if (k < 128) {
      v = roots[((size_t)l * 128 + k) * 128 + f];
    } else {
      int r = (k - 128) >> 7, d = (k - 128) & 127;
      const float* cp = comps + ((size_t)l * R_REL + r) * 8;
      const float* bp = bases + (((size_t)l * 8) * 128 + d) * 128 + f;
      float s = 0.f;
#pragma unroll
      for (int b = 0; b < 8; ++b) s += cp[b] * bp[(size_t)b * 128 * 128];
      v = s;
    }
    wcat2T[t] = f2bf(v);
  } else {
    int u = t - WCAT_ELEMS;
    if (u < HID * IN_C) {
      int m = u >> 8, k = u & 255;
      w1T[m * IN_C + k] = f2bf(w1[k * HID + m]);
    }
  }
}

// ------------------------------------------------- histogram (dst,rel) + rank
__global__ __launch_bounds__(256) void hist_kernel(
    const int* __restrict__ ei, const int* __restrict__ et,
    int* __restrict__ cntRel, int* __restrict__ erank)
{
  int e = blockIdx.x * 256 + threadIdx.x;
  if (e >= E_EDGES) return;
  int seg = ei[E_EDGES + e] * R_REL + et[e];
  erank[e] = atomicAdd(&cntRel[seg], 1);
}

// ---------------------------------------------------------------- scan over NR
__global__ __launch_bounds__(256) void scanA_kernel(
    const int* __restrict__ cnt, int* __restrict__ tmpOff,
    int* __restrict__ blockSums)
{
  __shared__ int s[256];
  int i = blockIdx.x * 256 + threadIdx.x;
  int v = (i < NR) ? cnt[i] : 0;
  s[threadIdx.x] = v;
  __syncthreads();
#pragma unroll
  for (int d = 1; d < 256; d <<= 1) {
    int t = (threadIdx.x >= d) ? s[threadIdx.x - d] : 0;
    __syncthreads();
    s[threadIdx.x] += t;
    __syncthreads();
  }
  if (i < NR) tmpOff[i] = s[threadIdx.x] - v;   // exclusive within block
  if (threadIdx.x == 255) blockSums[blockIdx.x] = s[255];
}

// scanC: each block sums blockSums[0..bid) itself (raw sums from scanA);
// no serial scanB kernel needed. <=6 loads/thread + tree reduce.
__global__ __launch_bounds__(256) void scanC_kernel(
    const int* __restrict__ tmpOff, const int* __restrict__ blockSums,
    int* __restrict__ drs)
{
  __shared__ int red[256];
  const int bid = blockIdx.x;
  int part = 0;
  for (int i = threadIdx.x; i < bid; i += 256) part += blockSums[i];
  red[threadIdx.x] = part;
  __syncthreads();
#pragma unroll
  for (int d = 128; d > 0; d >>= 1) {
    if (threadIdx.x < d) red[threadIdx.x] += red[threadIdx.x + d];
    __syncthreads();
  }
  const int base = red[0];
  int i = bid * 256 + threadIdx.x;
  if (i < NR) drs[i] = tmpOff[i] + base;
  if (i == 0) drs[NR] = E_EDGES;
}

// ---------------------------------------------------------------- placement
// Pure scatter: pos = drs[seg] + erank[e]. No atomics.
__global__ __launch_bounds__(256) void place_kernel(
    const int* __restrict__ ei, const int* __restrict__ et,
    const int* __restrict__ drs, const int* __restrict__ erank,
    unsigned short* __restrict__ esrc)
{
  int e = blockIdx.x * 256 + threadIdx.x;
  if (e >= E_EDGES) return;
  int seg = ei[E_EDGES + e] * R_REL + et[e];
  int pos = drs[seg] + erank[e];
  esrc[pos] = (unsigned short)ei[e];   // src < 50000 < 65536
}

// ---------------------------------------------------------------- aggregation
// One wave per dst; 64 lanes x 2 dims = full 256B curA row per edge (coalesced).
// Edges sorted (dst,rel). Batch-prefetch up to 16 independent row loads into
// statically-indexed registers, then segmented accumulate with a uniform
// relation-boundary walk. 5x-probed floor: ~61us.
constexpr int AGG_NPF = 16;
__global__ __launch_bounds__(256) void agg_reg_kernel(
    const unsigned short* __restrict__ curA,   // [N,128] bf16
    const unsigned short* __restrict__ esrc,   // sorted by (dst,rel)
    const int* __restrict__ drs,               // [N*R+1] segment starts
    unsigned short* __restrict__ aggB)         // [N,896] bf16
{
  const int tid  = threadIdx.x;
  const int lane = tid & 63;
  const int dst  = blockIdx.x * 4 + (tid >> 6);
  if (dst >= N_NODES) return;
  const int segBase = dst * R_REL;

  int bnd = drs[segBase + (lane & 7)];
  const int a0    = __shfl(bnd, 0);
  const int total = __shfl(bnd, 7) - a0;

  int pk = 0;
  if (lane < total) pk = (int)esrc[a0 + lane];   // covers total<=64 (deg avg 12)

  const unsigned* colp = (const unsigned*)curA + lane;   // row stride = 64 uints
  unsigned* outp = (unsigned*)(aggB + (size_t)dst * AGG_COLS) + lane;

  int r = 0;
  int segStart = 0;
  int segEnd = __shfl(bnd, 1) - a0;
  float sx = 0.f, sy = 0.f;
  int pos = 0;

#define AGG_FLUSH()                                                        \
  while (r < R_REL && segEnd == pos) {                                     \
    int c = segEnd - segStart;                                             \
    float sc = (c > 0) ? 1.0f / (float)c : 0.f;                            \
    unsigned pck = (unsigned)f2bf(sx * sc) | ((unsigned)f2bf(sy * sc) << 16); \
    outp[r * 64] = pck;                                                    \
    sx = 0.f; sy = 0.f;                                                    \
    segStart = segEnd;                                                     \
    ++r;                                                                   \
    segEnd = (r < R_REL) ? (__shfl(bnd, r + 1) - a0) : 0x7FFFFFFF;         \
  }

  AGG_FLUSH();

  for (int base = 0; base < total; base += AGG_NPF) {
    const int cnt = min(total - base, AGG_NPF);
    unsigned v[AGG_NPF];
#pragma unroll
    for (int e = 0; e < AGG_NPF; ++e) {
      if (e < cnt) {
        int idx = base + e;
        int src = (idx < 64) ? __shfl(pk, idx) : (int)esrc[a0 + idx];
        v[e] = colp[src * 64];
      }
    }
#pragma unroll
    for (int e = 0; e < AGG_NPF; ++e) {
      if (e >= cnt) break;
      unsigned u = v[e];
      sx += __uint_as_float(u << 16);            // lo bf16
      sy += __uint_as_float(u & 0xFFFF0000u);    // hi bf16
      ++pos;
      AGG_FLUSH();
    }
  }
#undef AGG_FLUSH
}

// ---------------------------------------------------------------- lin1 MFMA GEMM
// M=64 tile (grid 782), K=256 in 2 phases; x read fp32 + cast DURING staging.
// Output: b0 = bf16(t0*(x@w1+b1)) ONLY (no fp32 hidden).
__global__ __launch_bounds__(256) void gemm_lin1(
    const float* __restrict__ x,              // [N,256] fp32
    const unsigned short* __restrict__ BT,    // w1T [128,256] bf16
    const float* __restrict__ bias,
    const float* __restrict__ temp,
    unsigned short* __restrict__ b0out)       // [N,128] bf16
{
  __shared__ unsigned short Atile[64][136];    // 17.4 KB
  __shared__ unsigned short Btile[128][136];   // 34.8 KB
  const int tid  = threadIdx.x;
  const int row0 = blockIdx.x * 64;
  const int lane = tid & 63;
  const int wid  = tid >> 6;
  const int wrow = (wid & 1) * 32;
  const int wcol = (wid >> 1) * 64;
  const int l15  = lane & 15;
  const int quad = lane >> 4;

  floatx4 acc[2][4] = {};

  for (int k0 = 0; k0 < IN_C; k0 += 128) {
#pragma unroll
    for (int it = 0; it < 4; ++it) {
      int chunk = it * 256 + tid;
      int r = chunk >> 4, cc = (chunk & 15) << 3;
      int grow = row0 + r;
      uint4 va = make_uint4(0u, 0u, 0u, 0u);
      if (grow < N_NODES) {
        const float* xp = x + (size_t)grow * IN_C + k0 + cc;
        float4 f0 = *(const float4*)xp;
        float4 f1 = *(const float4*)(xp + 4);
        va.x = (unsigned)f2bf(f0.x) | ((unsigned)f2bf(f0.y) << 16);
        va.y = (unsigned)f2bf(f0.z) | ((unsigned)f2bf(f0.w) << 16);
        va.z = (unsigned)f2bf(f1.x) | ((unsigned)f2bf(f1.y) << 16);
        va.w = (unsigned)f2bf(f1.z) | ((unsigned)f2bf(f1.w) << 16);
      }
      *(uint4*)(&Atile[r][cc]) = va;
    }
#pragma unroll
    for (int it = 0; it < 8; ++it) {
      int chunk = it * 256 + tid;
      int n = chunk >> 4, cc = (chunk & 15) << 3;
      *(uint4*)(&Btile[n][cc]) =
          *(const uint4*)(BT + (size_t)n * IN_C + k0 + cc);
    }
    __syncthreads();
#pragma unroll
    for (int ks = 0; ks < 4; ++ks) {
      int kc = ks * 32 + quad * 8;
      short8 af[2], bfr[4];
#pragma unroll
      for (int i = 0; i < 2; ++i)
        af[i] = *(const short8*)(&Atile[wrow + i * 16 + l15][kc]);
#pragma unroll
      for (int j = 0; j < 4; ++j)
        bfr[j] = *(const short8*)(&Btile[wcol + j * 16 + l15][kc]);
#pragma unroll
      for (int i = 0; i < 2; ++i)
#pragma unroll
        for (int j = 0; j < 4; ++j)
          acc[i][j] = __builtin_amdgcn_mfma_f32_16x16x32_bf16(
              af[i], bfr[j], acc[i][j], 0, 0, 0);
    }
    __syncthreads();
  }

  float t0 = temp[0];
#pragma unroll
  for (int i = 0; i < 2; ++i) {
    int lrow0 = wrow + i * 16 + quad * 4;
#pragma unroll
    for (int j = 0; j < 4; ++j) {
      int gcol = wcol + j * 16 + l15;
      float bb = bias[gcol];
#pragma unroll
      for (int r = 0; r < 4; ++r)
        Atile[lrow0 + r][gcol] = f2bf(t0 * (acc[i][j][r] + bb));
    }
  }
  __syncthreads();
#pragma unroll
  for (int it = 0; it < 4; ++it) {
    int chunk = it * 256 + tid;
    int r = chunk >> 4, cc = (chunk & 15) << 3;
    int grow = row0 + r;
    if (grow < N_NODES)
      *(uint4*)(b0out + (size_t)grow * HID + cc) = *(const uint4*)(&Atile[r][cc]);
  }
}

// ---------------------------------------------------------------- layer MFMA GEMM
// M=128 tile (grid 391), 4 waves each 64x64 (acc 4x4). A direct from global
// (curA p=0, aggB p>0), LDS = B panel only (34.8 KB, reused as C transpose).
// l<2: bout = bf16(relu(acc+bias)). l=2 (isLast): NO bout store; instead
// out = (b0 + t1*b1 + t2*curA + t3*c) @ w2 + b2bias  (final_kernel folded).
__global__ __launch_bounds__(256) void gemm_layer(
    const unsigned short* __restrict__ curA,   // [N,128] bf16 (in, = b_l)
    const unsigned short* __restrict__ aggB,   // [N,896] bf16
    const unsigned short* __restrict__ BT,     // wcat2T [128][1024] bf16
    const float* __restrict__ bias,
    unsigned short* __restrict__ bout,         // [N,128] bf16 (out, = b_{l+1})
    const unsigned short* __restrict__ b0g,    // bl[0] (for isLast fold)
    const unsigned short* __restrict__ b1g,    // bl[1]
    const float* __restrict__ temp,
    const float* __restrict__ w2,              // [128,2] fp32
    const float* __restrict__ b2bias,          // [2]
    float* __restrict__ out,                   // [N,2] fp32
    int layer)
{
  __shared__ unsigned short Btile[128][136];   // 34.8 KB (B panel / C transpose)
  const int tid  = threadIdx.x;
  const int row0 = blockIdx.x * 128;
  const int lane = tid & 63;
  const int wid  = tid >> 6;
  const int wrow = (wid & 1) * 64;
  const int wcol = (wid >> 1) * 64;
  const int l15  = lane & 15;
  const int quad = lane >> 4;

  floatx4 acc[4][4] = {};

  for (int p = 0; p < 8; ++p) {
#pragma unroll
    for (int it = 0; it < 8; ++it) {
      int chunk = it * 256 + tid;
      int n = chunk >> 4, cc = (chunk & 15) << 3;
      *(uint4*)(&Btile[n][cc]) =
          *(const uint4*)(BT + (size_t)n * K_CAT + p * 128 + cc);
    }
    __syncthreads();
#pragma unroll
    for (int ks = 0; ks < 4; ++ks) {
      int kc = ks * 32 + quad * 8;
      short8 af[4], bfr[4];
#pragma unroll
      for (int i = 0; i < 4; ++i) {
        int grow = row0 + wrow + i * 16 + l15;
        short8 v = {};
        if (grow < N_NODES) {
          const unsigned short* ap = (p == 0)
              ? curA + (size_t)grow * HID + kc
              : aggB + (size_t)grow * AGG_COLS + (p - 1) * 128 + kc;
          v = *(const short8*)ap;
        }
        af[i] = v;
      }
#pragma unroll
      for (int j = 0; j < 4; ++j)
        bfr[j] = *(const short8*)(&Btile[wcol + j * 16 + l15][kc]);
#pragma unroll
      for (int i = 0; i < 4; ++i)
#pragma unroll
        for (int j = 0; j < 4; ++j)
          acc[i][j] = __builtin_amdgcn_mfma_f32_16x16x32_bf16(
              af[i], bfr[j], acc[i][j], 0, 0, 0);
    }
    __syncthreads();
  }

  // C transpose into Btile: c = (l<2?relu:id)(acc+bias) as bf16.
  const bool isLast = (layer == L_LAYERS - 1);
#pragma unroll
  for (int i = 0; i < 4; ++i) {
    int lrow0 = wrow + i * 16 + quad * 4;
#pragma unroll
    for (int j = 0; j < 4; ++j) {
      int gcol = wcol + j * 16 + l15;
      float bb = bias[gcol];
#pragma unroll
      for (int r = 0; r < 4; ++r) {
        float c = acc[i][j][r] + bb;
        if (!isLast) c = fmaxf(c, 0.f);
        Btile[lrow0 + r][gcol] = f2bf(c);
      }
    }
  }
  __syncthreads();

  if (!isLast) {
    // store bout tile (b_{l+1})
#pragma unroll
    for (int it = 0; it < 8; ++it) {
      int chunk = it * 256 + tid;
      int r = chunk >> 4, cc = (chunk & 15) << 3;
      int grow = row0 + r;
      if (grow < N_NODES)
        *(uint4*)(bout + (size_t)grow * HID + cc) = *(const uint4*)(&Btile[r][cc]);
    }
  } else {
    // folded final: 2 threads/row, 64 dims each; h = b0 + t1*b1 + t2*b2 + t3*c
    // (b2 term = curA row). out = h @ w2 + b2bias. No b3 store needed.
    float t1 = temp[1], t2 = temp[2], t3 = temp[3];
    int r = tid >> 1, half = tid & 1;
    int grow = row0 + r;
    float s0 = 0.f, s1 = 0.f;
    if (grow < N_NODES) {
      const unsigned* p0 = (const unsigned*)(b0g  + (size_t)grow * HID) + half * 32;
      const unsigned* p1 = (const unsigned*)(b1g  + (size_t)grow * HID) + half * 32;
      const unsigned* p2 = (const unsigned*)(curA + (size_t)grow * HID) + half * 32;
#pragma unroll
      for (int c = 0; c < 32; ++c) {
        unsigned u0 = p0[c], u1 = p1[c], u2 = p2[c];
        unsigned uc = *(const unsigned*)(&Btile[r][half * 64 + c * 2]);
        float hx = bf2f((unsigned short)(u0 & 0xFFFF)) +
                   t1 * bf2f((unsigned short)(u1 & 0xFFFF)) +
                   t2 * bf2f((unsigned short)(u2 & 0xFFFF)) +
                   t3 * bf2f((unsigned short)(uc & 0xFFFF));
        float hy = bf2f((unsigned short)(u0 >> 16)) +
                   t1 * bf2f((unsigned short)(u1 >> 16)) +
                   t2 * bf2f((unsigned short)(u2 >> 16)) +
                   t3 * bf2f((unsigned short)(uc >> 16));
        int d = half * 64 + c * 2;
        s0 += hx * w2[d * 2 + 0] + hy * w2[(d + 1) * 2 + 0];
        s1 += hx * w2[d * 2 + 1] + hy * w2[(d + 1) * 2 + 1];
      }
    }
    s0 += __shfl_xor(s0, 1);
    s1 += __shfl_xor(s1, 1);
    if (half == 0 && grow < N_NODES) {
      out[grow * 2 + 0] = s0 + b2bias[0];
      out[grow * 2 + 1] = s1 + b2bias[1];
    }
  }
}

// ---------------------------------------------------------------- launcher
extern "C" void kernel_launch(void* const* d_in, const int* in_sizes, int n_in,
                              void* d_out, int out_size, void* d_ws, size_t ws_size,
                              hipStream_t stream) {
  const float* x     = (const float*)d_in[0];
  const int*   ei    = (const int*)d_in[1];
  const int*   et    = (const int*)d_in[2];
  const float* temp  = (const float*)d_in[3];
  const float* w1    = (const float*)d_in[4];
  const float* b1    = (const float*)d_in[5];
  const float* w2    = (const float*)d_in[6];
  const float* b2    = (const float*)d_in[7];
  const float* comps = (const float*)d_in[8];
  const float* bases = (const float*)d_in[9];
  const float* roots = (const float*)d_in[10];
  const float* cbias = (const float*)d_in[11];

  char* ws = (char*)d_ws;
  size_t off = 0;
  auto take = [&](size_t bytes) {
    char* p = ws + off;
    off = (off + bytes + 255) & ~(size_t)255;
    return p;
  };
  unsigned short* wcat2T = (unsigned short*)take((size_t)WCAT_ELEMS * 2);  // 0.8 MB
  unsigned short* w1T    = (unsigned short*)take((size_t)HID * IN_C * 2);  // 64 KB
  int*   cntRel  = (int*)take((size_t)NR * 4);                  // 1.4 MB
  int*   tmpOffR = (int*)take((size_t)NR * 4);                  // 1.4 MB
  int*   blockSumsR = (int*)take((size_t)SCANR_BLOCKS * 4);
  int*   drs     = (int*)take((size_t)(NR + 1) * 4);            // 1.4 MB
  int*   erank   = (int*)take((size_t)E_EDGES * 4);             // 2.4 MB
  unsigned short* esrc = (unsigned short*)take((size_t)E_EDGES * 2); // 1.2 MB
  unsigned short* bl[L_LAYERS + 1];
  for (int i = 0; i <= L_LAYERS; ++i)
    bl[i] = (unsigned short*)take((size_t)N_NODES * HID * 2);   // 4 x 12.8 MB
  unsigned short* aggB = (unsigned short*)take((size_t)N_NODES * AGG_COLS * 2); // 89.6 MB

  hipLaunchKernelGGL(prep_weights,
                     dim3((WCAT_ELEMS + HID * IN_C + 255) / 256), dim3(256),
                     0, stream, w1, comps, bases, roots, w1T, wcat2T, cntRel);
  hipLaunchKernelGGL(hist_kernel, dim3((E_EDGES + 255) / 256), dim3(256), 0,
                     stream, ei, et, cntRel, erank);
  hipLaunchKernelGGL(scanA_kernel, dim3(SCANR_BLOCKS), dim3(256), 0, stream,
                     cntRel, tmpOffR, blockSumsR);
  hipLaunchKernelGGL(scanC_kernel, dim3(SCANR_BLOCKS), dim3(256), 0, stream,
                     tmpOffR, blockSumsR, drs);
  hipLaunchKernelGGL(place_kernel, dim3((E_EDGES + 255) / 256), dim3(256), 0,
                     stream, ei, et, drs, erank, esrc);

  const int rowBlocks64  = (N_NODES + 63) / 64;     // 782
  const int rowBlocks128 = (N_NODES + 127) / 128;   // 391
  hipLaunchKernelGGL(gemm_lin1, dim3(rowBlocks64), dim3(256), 0, stream,
                     x, w1T, b1, temp, bl[0]);

  for (int l = 0; l < L_LAYERS; ++l) {
    hipLaunchKernelGGL(agg_reg_kernel, dim3((N_NODES + 3) / 4), dim3(256),
                       0, stream, bl[l], esrc, drs, aggB);
    hipLaunchKernelGGL(gemm_layer, dim3(rowBlocks128), dim3(256), 0, stream,
                       bl[l], aggB, wcat2T + (size_t)l * 128 * K_CAT,
                       cbias + (size_t)l * HID, bl[l + 1],
                       bl[0], bl[1], temp, w2, b2, (float*)d_out, l);
  }
}

// Round 11
// 473.180 us; speedup vs baseline: 1.1140x; 1.1140x over previous
//
#include <hip/hip_runtime.h>
#include <cstdint>

// RGPR-GNN (GPR-GNN + RGCN basis-decomp convs) for MI355X.
// R22: REVERT R21's lin2 fold (VGPR 76->132, occupancy 8%, +48us — second
// epilogue-fold regression; rule: keep layer-GEMM epilogues minimal).
// = R18 exactly (best verified 478.6us), PLUS the two harmless launch cuts:
//  - scanB deleted (scanC computes its own block base from raw blockSums).
//  - memset deleted (prep_weights zeroes cntRel).
// Per layer:
//   agg_reg:   one wave per dst, (dst,rel)-sorted edges, register accum.
//              5x-probed floor ~61us (MLP++, wave/seg, 2 fusions, transform).
//   gemm_layer: M=128 direct-A (R18, VGPR 76), c=[curA|agg]@Wcat2+bias.
// Edge sort by (dst,rel) runs ONCE: hist(+rank) -> scanA/scanC -> placement.

constexpr int N_NODES  = 50000;
constexpr int E_EDGES  = 600000;
constexpr int R_REL    = 7;
constexpr int HID      = 128;
constexpr int IN_C     = 256;
constexpr int L_LAYERS = 3;
constexpr int AGG_COLS = 896;           // 7*128 aggregated message columns
constexpr int K_CAT    = 1024;          // 128 self + 896 agg
constexpr int NR       = N_NODES * R_REL;            // 350000 segments
constexpr int SCANR_BLOCKS = (NR + 255) / 256;       // 1368
constexpr int WCAT_ELEMS = L_LAYERS * 128 * K_CAT;   // 393216

#define DEVI __device__ __forceinline__

using short8  = __attribute__((ext_vector_type(8))) short;
using floatx4 = __attribute__((ext_vector_type(4))) float;

DEVI unsigned short f2bf(float f) {
  unsigned u = __float_as_uint(f);
  unsigned r = (u + 0x7FFFu + ((u >> 16) & 1u)) >> 16;  // RNE
  return (unsigned short)r;
}
DEVI float bf2f(unsigned short h) { return __uint_as_float(((unsigned)h) << 16); }

// ---------------------------------------------------------------- weight prep
// t < WCAT_ELEMS: wcat2T[L][f=128][k=1024]; else w1T [128][256].
// Also zeroes cntRel[t] for t < NR (replaces the memset dispatch).
__global__ __launch_bounds__(256) void prep_weights(
    const float* __restrict__ w1,
    const float* __restrict__ comps,   // [L,R,8]
    const float* __restrict__ bases,   // [L,8,128,128]
    const float* __restrict__ roots,   // [L,128,128]
    unsigned short* __restrict__ w1T,
    unsigned short* __restrict__ wcat2T,
    int* __restrict__ cntRel)
{
  int t = blockIdx.x * 256 + threadIdx.x;
  if (t < NR) cntRel[t] = 0;
  if (t < WCAT_ELEMS) {
    int l   = t >> 17;
    int rem = t & 131071;
    int f   = rem >> 10;
    int k   = rem & 1023;
    float v;
    if (k < 128) {
      v = roots[((size_t)l * 128 + k) * 128 + f];
    } else {
      int r = (k - 128) >> 7, d = (k - 128) & 127;
      const float* cp = comps + ((size_t)l * R_REL + r) * 8;
      const float* bp = bases + (((size_t)l * 8) * 128 + d) * 128 + f;
      float s = 0.f;
#pragma unroll
      for (int b = 0; b < 8; ++b) s += cp[b] * bp[(size_t)b * 128 * 128];
      v = s;
    }
    wcat2T[t] = f2bf(v);
  } else {
    int u = t - WCAT_ELEMS;
    if (u < HID * IN_C) {
      int m = u >> 8, k = u & 255;
      w1T[m * IN_C + k] = f2bf(w1[k * HID + m]);
    }
  }
}

// ------------------------------------------------- histogram (dst,rel) + rank
__global__ __launch_bounds__(256) void hist_kernel(
    const int* __restrict__ ei, const int* __restrict__ et,
    int* __restrict__ cntRel, int* __restrict__ erank)
{
  int e = blockIdx.x * 256 + threadIdx.x;
  if (e >= E_EDGES) return;
  int seg = ei[E_EDGES + e] * R_REL + et[e];
  erank[e] = atomicAdd(&cntRel[seg], 1);
}

// ---------------------------------------------------------------- scan over NR
__global__ __launch_bounds__(256) void scanA_kernel(
    const int* __restrict__ cnt, int* __restrict__ tmpOff,
    int* __restrict__ blockSums)
{
  __shared__ int s[256];
  int i = blockIdx.x * 256 + threadIdx.x;
  int v = (i < NR) ? cnt[i] : 0;
  s[threadIdx.x] = v;
  __syncthreads();
#pragma unroll
  for (int d = 1; d < 256; d <<= 1) {
    int t = (threadIdx.x >= d) ? s[threadIdx.x - d] : 0;
    __syncthreads();
    s[threadIdx.x] += t;
    __syncthreads();
  }
  if (i < NR) tmpOff[i] = s[threadIdx.x] - v;   // exclusive within block
  if (threadIdx.x == 255) blockSums[blockIdx.x] = s[255];
}

// scanC: each block sums blockSums[0..bid) itself (raw sums from scanA);
// no serial scanB kernel needed. <=6 loads/thread + tree reduce.
__global__ __launch_bounds__(256) void scanC_kernel(
    const int* __restrict__ tmpOff, const int* __restrict__ blockSums,
    int* __restrict__ drs)
{
  __shared__ int red[256];
  const int bid = blockIdx.x;
  int part = 0;
  for (int i = threadIdx.x; i < bid; i += 256) part += blockSums[i];
  red[threadIdx.x] = part;
  __syncthreads();
#pragma unroll
  for (int d = 128; d > 0; d >>= 1) {
    if (threadIdx.x < d) red[threadIdx.x] += red[threadIdx.x + d];
    __syncthreads();
  }
  const int base = red[0];
  int i = bid * 256 + threadIdx.x;
  if (i < NR) drs[i] = tmpOff[i] + base;
  if (i == 0) drs[NR] = E_EDGES;
}

// ---------------------------------------------------------------- placement
// Pure scatter: pos = drs[seg] + erank[e]. No atomics.
__global__ __launch_bounds__(256) void place_kernel(
    const int* __restrict__ ei, const int* __restrict__ et,
    const int* __restrict__ drs, const int* __restrict__ erank,
    unsigned short* __restrict__ esrc)
{
  int e = blockIdx.x * 256 + threadIdx.x;
  if (e >= E_EDGES) return;
  int seg = ei[E_EDGES + e] * R_REL + et[e];
  int pos = drs[seg] + erank[e];
  esrc[pos] = (unsigned short)ei[e];   // src < 50000 < 65536
}

// ---------------------------------------------------------------- aggregation
// One wave per dst; 64 lanes x 2 dims = full 256B curA row per edge (coalesced).
// Edges sorted (dst,rel). Batch-prefetch up to 16 independent row loads into
// statically-indexed registers, then segmented accumulate with a uniform
// relation-boundary walk. 5x-probed floor: ~61us.
constexpr int AGG_NPF = 16;
__global__ __launch_bounds__(256) void agg_reg_kernel(
    const unsigned short* __restrict__ curA,   // [N,128] bf16
    const unsigned short* __restrict__ esrc,   // sorted by (dst,rel)
    const int* __restrict__ drs,               // [N*R+1] segment starts
    unsigned short* __restrict__ aggB)         // [N,896] bf16
{
  const int tid  = threadIdx.x;
  const int lane = tid & 63;
  const int dst  = blockIdx.x * 4 + (tid >> 6);
  if (dst >= N_NODES) return;
  const int segBase = dst * R_REL;

  int bnd = drs[segBase + (lane & 7)];
  const int a0    = __shfl(bnd, 0);
  const int total = __shfl(bnd, 7) - a0;

  int pk = 0;
  if (lane < total) pk = (int)esrc[a0 + lane];   // covers total<=64 (deg avg 12)

  const unsigned* colp = (const unsigned*)curA + lane;   // row stride = 64 uints
  unsigned* outp = (unsigned*)(aggB + (size_t)dst * AGG_COLS) + lane;

  int r = 0;
  int segStart = 0;
  int segEnd = __shfl(bnd, 1) - a0;
  float sx = 0.f, sy = 0.f;
  int pos = 0;

#define AGG_FLUSH()                                                        \
  while (r < R_REL && segEnd == pos) {                                     \
    int c = segEnd - segStart;                                             \
    float sc = (c > 0) ? 1.0f / (float)c : 0.f;                            \
    unsigned pck = (unsigned)f2bf(sx * sc) | ((unsigned)f2bf(sy * sc) << 16); \
    outp[r * 64] = pck;                                                    \
    sx = 0.f; sy = 0.f;                                                    \
    segStart = segEnd;                                                     \
    ++r;                                                                   \
    segEnd = (r < R_REL) ? (__shfl(bnd, r + 1) - a0) : 0x7FFFFFFF;         \
  }

  AGG_FLUSH();

  for (int base = 0; base < total; base += AGG_NPF) {
    const int cnt = min(total - base, AGG_NPF);
    unsigned v[AGG_NPF];
#pragma unroll
    for (int e = 0; e < AGG_NPF; ++e) {
      if (e < cnt) {
        int idx = base + e;
        int src = (idx < 64) ? __shfl(pk, idx) : (int)esrc[a0 + idx];
        v[e] = colp[src * 64];
      }
    }
#pragma unroll
    for (int e = 0; e < AGG_NPF; ++e) {
      if (e >= cnt) break;
      unsigned u = v[e];
      sx += __uint_as_float(u << 16);            // lo bf16
      sy += __uint_as_float(u & 0xFFFF0000u);    // hi bf16
      ++pos;
      AGG_FLUSH();
    }
  }
#undef AGG_FLUSH
}

// ---------------------------------------------------------------- lin1 MFMA GEMM
// M=64 tile (grid 782), K=256 in 2 phases; x read fp32 + cast DURING staging.
// Output: b0 = bf16(t0*(x@w1+b1)) ONLY (no fp32 hidden).
__global__ __launch_bounds__(256) void gemm_lin1(
    const float* __restrict__ x,              // [N,256] fp32
    const unsigned short* __restrict__ BT,    // w1T [128,256] bf16
    const float* __restrict__ bias,
    const float* __restrict__ temp,
    unsigned short* __restrict__ b0out)       // [N,128] bf16
{
  __shared__ unsigned short Atile[64][136];    // 17.4 KB
  __shared__ unsigned short Btile[128][136];   // 34.8 KB
  const int tid  = threadIdx.x;
  const int row0 = blockIdx.x * 64;
  const int lane = tid & 63;
  const int wid  = tid >> 6;
  const int wrow = (wid & 1) * 32;
  const int wcol = (wid >> 1) * 64;
  const int l15  = lane & 15;
  const int quad = lane >> 4;

  floatx4 acc[2][4] = {};

  for (int k0 = 0; k0 < IN_C; k0 += 128) {
#pragma unroll
    for (int it = 0; it < 4; ++it) {
      int chunk = it * 256 + tid;
      int r = chunk >> 4, cc = (chunk & 15) << 3;
      int grow = row0 + r;
      uint4 va = make_uint4(0u, 0u, 0u, 0u);
      if (grow < N_NODES) {
        const float* xp = x + (size_t)grow * IN_C + k0 + cc;
        float4 f0 = *(const float4*)xp;
        float4 f1 = *(const float4*)(xp + 4);
        va.x = (unsigned)f2bf(f0.x) | ((unsigned)f2bf(f0.y) << 16);
        va.y = (unsigned)f2bf(f0.z) | ((unsigned)f2bf(f0.w) << 16);
        va.z = (unsigned)f2bf(f1.x) | ((unsigned)f2bf(f1.y) << 16);
        va.w = (unsigned)f2bf(f1.z) | ((unsigned)f2bf(f1.w) << 16);
      }
      *(uint4*)(&Atile[r][cc]) = va;
    }
#pragma unroll
    for (int it = 0; it < 8; ++it) {
      int chunk = it * 256 + tid;
      int n = chunk >> 4, cc = (chunk & 15) << 3;
      *(uint4*)(&Btile[n][cc]) =
          *(const uint4*)(BT + (size_t)n * IN_C + k0 + cc);
    }
    __syncthreads();
#pragma unroll
    for (int ks = 0; ks < 4; ++ks) {
      int kc = ks * 32 + quad * 8;
      short8 af[2], bfr[4];
#pragma unroll
      for (int i = 0; i < 2; ++i)
        af[i] = *(const short8*)(&Atile[wrow + i * 16 + l15][kc]);
#pragma unroll
      for (int j = 0; j < 4; ++j)
        bfr[j] = *(const short8*)(&Btile[wcol + j * 16 + l15][kc]);
#pragma unroll
      for (int i = 0; i < 2; ++i)
#pragma unroll
        for (int j = 0; j < 4; ++j)
          acc[i][j] = __builtin_amdgcn_mfma_f32_16x16x32_bf16(
              af[i], bfr[j], acc[i][j], 0, 0, 0);
    }
    __syncthreads();
  }

  float t0 = temp[0];
#pragma unroll
  for (int i = 0; i < 2; ++i) {
    int lrow0 = wrow + i * 16 + quad * 4;
#pragma unroll
    for (int j = 0; j < 4; ++j) {
      int gcol = wcol + j * 16 + l15;
      float bb = bias[gcol];
#pragma unroll
      for (int r = 0; r < 4; ++r)
        Atile[lrow0 + r][gcol] = f2bf(t0 * (acc[i][j][r] + bb));
    }
  }
  __syncthreads();
#pragma unroll
  for (int it = 0; it < 4; ++it) {
    int chunk = it * 256 + tid;
    int r = chunk >> 4, cc = (chunk & 15) << 3;
    int grow = row0 + r;
    if (grow < N_NODES)
      *(uint4*)(b0out + (size_t)grow * HID + cc) = *(const uint4*)(&Atile[r][cc]);
  }
}

// ---------------------------------------------------------------- layer MFMA GEMM
// M=128 tile (grid 391), 4 waves each 64x64 (acc 4x4). A fragments read
// DIRECT from global (curA p=0, aggB p>0): 16B/lane contiguous, rows read
// exactly once -> no LDS A-stage, no A barrier. LDS = B panel only (34.8 KB),
// reused as the epilogue transpose buffer. Minimal epilogue (VGPR 76).
__global__ __launch_bounds__(256) void gemm_layer(
    const unsigned short* __restrict__ curA,   // [N,128] bf16 (in, = b_l)
    const unsigned short* __restrict__ aggB,   // [N,896] bf16
    const unsigned short* __restrict__ BT,     // wcat2T [128][1024] bf16
    const float* __restrict__ bias,
    unsigned short* __restrict__ bout,         // [N,128] bf16 (out, = b_{l+1})
    int layer)
{
  __shared__ unsigned short Btile[128][136];   // 34.8 KB (B panel / C transpose)
  const int tid  = threadIdx.x;
  const int row0 = blockIdx.x * 128;
  const int lane = tid & 63;
  const int wid  = tid >> 6;
  const int wrow = (wid & 1) * 64;
  const int wcol = (wid >> 1) * 64;
  const int l15  = lane & 15;
  const int quad = lane >> 4;

  floatx4 acc[4][4] = {};

  for (int p = 0; p < 8; ++p) {
#pragma unroll
    for (int it = 0; it < 8; ++it) {
      int chunk = it * 256 + tid;
      int n = chunk >> 4, cc = (chunk & 15) << 3;
      *(uint4*)(&Btile[n][cc]) =
          *(const uint4*)(BT + (size_t)n * K_CAT + p * 128 + cc);
    }
    __syncthreads();
#pragma unroll
    for (int ks = 0; ks < 4; ++ks) {
      int kc = ks * 32 + quad * 8;
      short8 af[4], bfr[4];
#pragma unroll
      for (int i = 0; i < 4; ++i) {
        int grow = row0 + wrow + i * 16 + l15;
        short8 v = {};
        if (grow < N_NODES) {
          const unsigned short* ap = (p == 0)
              ? curA + (size_t)grow * HID + kc
              : aggB + (size_t)grow * AGG_COLS + (p - 1) * 128 + kc;
          v = *(const short8*)ap;
        }
        af[i] = v;
      }
#pragma unroll
      for (int j = 0; j < 4; ++j)
        bfr[j] = *(const short8*)(&Btile[wcol + j * 16 + l15][kc]);
#pragma unroll
      for (int i = 0; i < 4; ++i)
#pragma unroll
        for (int j = 0; j < 4; ++j)
          acc[i][j] = __builtin_amdgcn_mfma_f32_16x16x32_bf16(
              af[i], bfr[j], acc[i][j], 0, 0, 0);
    }
    __syncthreads();
  }

  // epilogue: bout = bf16((l<2?relu:id)(acc+bias)) via LDS transpose (Btile).
  const bool isLast = (layer == L_LAYERS - 1);
#pragma unroll
  for (int i = 0; i < 4; ++i) {
    int lrow0 = wrow + i * 16 + quad * 4;
#pragma unroll
    for (int j = 0; j < 4; ++j) {
      int gcol = wcol + j * 16 + l15;
      float bb = bias[gcol];
#pragma unroll
      for (int r = 0; r < 4; ++r) {
        float c = acc[i][j][r] + bb;
        if (!isLast) c = fmaxf(c, 0.f);
        Btile[lrow0 + r][gcol] = f2bf(c);
      }
    }
  }
  __syncthreads();
#pragma unroll
  for (int it = 0; it < 8; ++it) {
    int chunk = it * 256 + tid;
    int r = chunk >> 4, cc = (chunk & 15) << 3;
    int grow = row0 + r;
    if (grow < N_NODES)
      *(uint4*)(bout + (size_t)grow * HID + cc) = *(const uint4*)(&Btile[r][cc]);
  }
}

// ---------------------------------------------------------------- final linear
// h[d] = b0 + temp[1]*b1 + temp[2]*b2 + temp[3]*b3 (bf16 terms), then lin2.
__global__ __launch_bounds__(256) void final_kernel(
    const unsigned short* __restrict__ b0, const unsigned short* __restrict__ b1,
    const unsigned short* __restrict__ b2v, const unsigned short* __restrict__ b3,
    const float* __restrict__ temp,
    const float* __restrict__ w2, const float* __restrict__ b2bias,
    float* __restrict__ out)
{
  int node = blockIdx.x * 4 + (threadIdx.x >> 6);
  int lane = threadIdx.x & 63;
  if (node >= N_NODES) return;
  float t1 = temp[1], t2 = temp[2], t3 = temp[3];
  size_t base = (size_t)node * 64 + lane;      // uint index: dims 2*lane,2*lane+1
  unsigned u0 = ((const unsigned*)b0)[base];
  unsigned u1 = ((const unsigned*)b1)[base];
  unsigned u2 = ((const unsigned*)b2v)[base];
  unsigned u3 = ((const unsigned*)b3)[base];
  float hx = bf2f((unsigned short)(u0 & 0xFFFF)) +
             t1 * bf2f((unsigned short)(u1 & 0xFFFF)) +
             t2 * bf2f((unsigned short)(u2 & 0xFFFF)) +
             t3 * bf2f((unsigned short)(u3 & 0xFFFF));
  float hy = bf2f((unsigned short)(u0 >> 16)) +
             t1 * bf2f((unsigned short)(u1 >> 16)) +
             t2 * bf2f((unsigned short)(u2 >> 16)) +
             t3 * bf2f((unsigned short)(u3 >> 16));
  int d0 = lane * 2, d1 = lane * 2 + 1;
  float a0 = hx * w2[d0 * 2 + 0] + hy * w2[d1 * 2 + 0];
  float a1 = hx * w2[d0 * 2 + 1] + hy * w2[d1 * 2 + 1];
#pragma unroll
  for (int off = 32; off > 0; off >>= 1) {
    a0 += __shfl_down(a0, off);
    a1 += __shfl_down(a1, off);
  }
  if (lane == 0) {
    out[node * 2 + 0] = a0 + b2bias[0];
    out[node * 2 + 1] = a1 + b2bias[1];
  }
}

// ---------------------------------------------------------------- launcher
extern "C" void kernel_launch(void* const* d_in, const int* in_sizes, int n_in,
                              void* d_out, int out_size, void* d_ws, size_t ws_size,
                              hipStream_t stream) {
  const float* x     = (const float*)d_in[0];
  const int*   ei    = (const int*)d_in[1];
  const int*   et    = (const int*)d_in[2];
  const float* temp  = (const float*)d_in[3];
  const float* w1    = (const float*)d_in[4];
  const float* b1    = (const float*)d_in[5];
  const float* w2    = (const float*)d_in[6];
  const float* b2    = (const float*)d_in[7];
  const float* comps = (const float*)d_in[8];
  const float* bases = (const float*)d_in[9];
  const float* roots = (const float*)d_in[10];
  const float* cbias = (const float*)d_in[11];

  char* ws = (char*)d_ws;
  size_t off = 0;
  auto take = [&](size_t bytes) {
    char* p = ws + off;
    off = (off + bytes + 255) & ~(size_t)255;
    return p;
  };
  unsigned short* wcat2T = (unsigned short*)take((size_t)WCAT_ELEMS * 2);  // 0.8 MB
  unsigned short* w1T    = (unsigned short*)take((size_t)HID * IN_C * 2);  // 64 KB
  int*   cntRel  = (int*)take((size_t)NR * 4);                  // 1.4 MB
  int*   tmpOffR = (int*)take((size_t)NR * 4);                  // 1.4 MB
  int*   blockSumsR = (int*)take((size_t)SCANR_BLOCKS * 4);
  int*   drs     = (int*)take((size_t)(NR + 1) * 4);            // 1.4 MB
  int*   erank   = (int*)take((size_t)E_EDGES * 4);             // 2.4 MB
  unsigned short* esrc = (unsigned short*)take((size_t)E_EDGES * 2); // 1.2 MB
  unsigned short* bl[L_LAYERS + 1];
  for (int i = 0; i <= L_LAYERS; ++i)
    bl[i] = (unsigned short*)take((size_t)N_NODES * HID * 2);   // 4 x 12.8 MB
  unsigned short* aggB = (unsigned short*)take((size_t)N_NODES * AGG_COLS * 2); // 89.6 MB

  hipLaunchKernelGGL(prep_weights,
                     dim3((WCAT_ELEMS + HID * IN_C + 255) / 256), dim3(256),
                     0, stream, w1, comps, bases, roots, w1T, wcat2T, cntRel);
  hipLaunchKernelGGL(hist_kernel, dim3((E_EDGES + 255) / 256), dim3(256), 0,
                     stream, ei, et, cntRel, erank);
  hipLaunchKernelGGL(scanA_kernel, dim3(SCANR_BLOCKS), dim3(256), 0, stream,
                     cntRel, tmpOffR, blockSumsR);
  hipLaunchKernelGGL(scanC_kernel, dim3(SCANR_BLOCKS), dim3(256), 0, stream,
                     tmpOffR, blockSumsR, drs);
  hipLaunchKernelGGL(place_kernel, dim3((E_EDGES + 255) / 256), dim3(256), 0,
                     stream, ei, et, drs, erank, esrc);

  const int rowBlocks64  = (N_NODES + 63) / 64;     // 782
  const int rowBlocks128 = (N_NODES + 127) / 128;   // 391
  hipLaunchKernelGGL(gemm_lin1, dim3(rowBlocks64), dim3(256), 0, stream,
                     x, w1T, b1, temp, bl[0]);

  for (int l = 0; l < L_LAYERS; ++l) {
    hipLaunchKernelGGL(agg_reg_kernel, dim3((N_NODES + 3) / 4), dim3(256),
                       0, stream, bl[l], esrc, drs, aggB);
    hipLaunchKernelGGL(gemm_layer, dim3(rowBlocks128), dim3(256), 0, stream,
                       bl[l], aggB, wcat2T + (size_t)l * 128 * K_CAT,
                       cbias + (size_t)l * HID, bl[l + 1], l);
  }

  hipLaunchKernelGGL(final_kernel, dim3((N_NODES + 3) / 4), dim3(256), 0, stream,
                     bl[0], bl[1], bl[2], bl[3], temp, w2, b2, (float*)d_out);
}